// Round 2
// baseline (152.246 us; speedup 1.0000x reference)
//
#include <hip/hip_runtime.h>

typedef _Float16 half8 __attribute__((ext_vector_type(8)));
typedef float    f32x16 __attribute__((ext_vector_type(16)));

constexpr int kH = 16;    // heads
constexpr int kO = 1024;  // codebook options
constexpr int kA = 128;   // head size
constexpr int kBS = 4096; // B*S positions
constexpr int MTILE = 256; // positions per block (4 msub x 64)
constexpr int NITER = 16;  // option-tiles (32 options) per nhalf

// ---- Pass 1: split W into fp16 hi/lo planes, packed fragment-major ----
// Packed (halfs): (h*32 + t)*8192 + plane*4096 + ks*512 + lane*8 + j
//   where t = o>>5, lane = half*32 + (o&31), ks = a>>4, half = (a>>3)&1, j = a&7
// Each (tile, plane, ks) chunk is 64 lanes x 16 B contiguous.
__global__ void split_w(const float* __restrict__ w, ushort* __restrict__ wp) {
    const int lane = threadIdx.x & 63;
    const int gw   = blockIdx.x * 4 + (threadIdx.x >> 6);
    const int ks   = lane >> 3;          // (2L)>>4
    const int half = (lane >> 2) & 1;    // ((2L)>>3)&1
    const int j    = (2 * lane) & 7;
#pragma unroll
    for (int q = 0; q < 4; ++q) {
        int r = gw * 4 + q;              // global row: h*1024 + o
        int h = r >> 10, o = r & 1023, t = o >> 5, o31 = o & 31;
        float2 v = *(const float2*)(w + r * kA + lane * 2);
        _Float16 h0 = (_Float16)v.x, h1 = (_Float16)v.y;
        _Float16 l0 = (_Float16)(v.x - (float)h0), l1 = (_Float16)(v.y - (float)h1);
        ushort2 hv = { __builtin_bit_cast(ushort, h0), __builtin_bit_cast(ushort, h1) };
        ushort2 lv = { __builtin_bit_cast(ushort, l0), __builtin_bit_cast(ushort, l1) };
        ushort* d = wp + (h * 32 + t) * 8192 + ks * 512 + (half * 32 + o31) * 8 + j;
        *(ushort2*)d = hv;               // plane 0 (hi)
        *(ushort2*)(d + 4096) = lv;      // plane 1 (lo)
    }
}

// ---- Pass 2: barrier-free W streaming global->reg (L1/L2-resident) ----
// Each wave owns 64 positions x 512 options; W fragments load directly into
// a 2-buffer register pipeline (A = wh, B = wl), issued one pass ahead so
// L2 latency hides under the previous pass's 16-MFMA cluster. No LDS for W,
// no DMA ring, no vmcnt asm: compiler emits counted vmcnt for reg loads.
// One bare s_barrier per tile bounds wave drift (keeps the 4 same-nhalf
// waves temporally close -> their identical W reads hit L1).
__launch_bounds__(512, 2)
__global__ void vq_argmax_gather(const float* __restrict__ x,
                                 const ushort* __restrict__ wp,
                                 const float* __restrict__ cb,
                                 float* __restrict__ out) {
    __shared__ float red_max[2][MTILE];
    __shared__ int   red_idx[2][MTILE];

    const int tid   = threadIdx.x;
    const int lane  = tid & 63;
    const int wv    = tid >> 6;     // 0..7
    const int nhalf = wv >> 2;      // option half (512 each)
    const int msub  = wv & 3;       // 64-position group
    const int bid   = blockIdx.x;
    // XCD-aware: XCD (bid&7) touches only heads {2x,2x+1} -> W+cb L2-resident
    const int h  = ((bid & 7) << 1) | ((bid >> 3) & 1);
    const int p0 = (bid >> 4) * MTILE;

    const int l31  = lane & 31;
    const int half = lane >> 5;

    // this wave's packed-W base: global tile t = nhalf*16 + it
    const ushort* wb = wp + (h * 32 + nhalf * 16) * 8192 + lane * 8;

    // stationary x fragments for BOTH row-tiles (fp32 -> fp16 hi/lo in-register)
    const int mrow0 = p0 + msub * 64 + l31;
    const float* xb0 = x + (mrow0 * kH + h) * kA + half * 8;
    const float* xb1 = xb0 + 32 * kH * kA;   // +32 positions
    half8 xh0[8], xl0[8], xh1[8], xl1[8];
    auto cvt8 = [&](const float* p, half8& hi, half8& lo) {
        float4 v0 = *(const float4*)(p);
        float4 v1 = *(const float4*)(p + 4);
        float va[8] = { v0.x, v0.y, v0.z, v0.w, v1.x, v1.y, v1.z, v1.w };
#pragma unroll
        for (int j = 0; j < 8; ++j) {
            _Float16 hj = (_Float16)va[j];
            hi[j] = hj;
            lo[j] = (_Float16)(va[j] - (float)hj);
        }
    };
#pragma unroll
    for (int ks = 0; ks < 8; ++ks) {
        cvt8(xb0 + ks * 16, xh0[ks], xl0[ks]);
        cvt8(xb1 + ks * 16, xh1[ks], xl1[ks]);
    }

    // preload tile 0's hi-plane fragments
    half8 A[8], Bf[8];
#pragma unroll
    for (int ks = 0; ks < 8; ++ks)
        A[ks] = *(const half8*)(wb + ks * 512);

    float best0 = -1e30f, best1 = -1e30f;
    int   bidx0 = 0,      bidx1 = 0;
    const int nwb = nhalf * (kO / 2);

    for (int it = 0; it < NITER; ++it) {
        __builtin_amdgcn_s_barrier();            // drift bound only (no waitcnt)
        const ushort* tb = wb + it * 8192;

        // issue lo-plane loads (consumed by pass 3) under passes 1-2
#pragma unroll
        for (int ks = 0; ks < 8; ++ks)
            Bf[ks] = *(const half8*)(tb + 4096 + ks * 512);

        f32x16 acc0 = {}, acc1 = {};
        // pass 1: wh x xh  (accumulation order identical to previous kernel)
#pragma unroll
        for (int ks = 0; ks < 8; ++ks) {
            acc0 = __builtin_amdgcn_mfma_f32_32x32x16_f16(A[ks], xh0[ks], acc0, 0, 0, 0);
            acc1 = __builtin_amdgcn_mfma_f32_32x32x16_f16(A[ks], xh1[ks], acc1, 0, 0, 0);
        }
        // pass 2: wh x xl
#pragma unroll
        for (int ks = 0; ks < 8; ++ks) {
            acc0 = __builtin_amdgcn_mfma_f32_32x32x16_f16(A[ks], xl0[ks], acc0, 0, 0, 0);
            acc1 = __builtin_amdgcn_mfma_f32_32x32x16_f16(A[ks], xl1[ks], acc1, 0, 0, 0);
        }
        // issue next tile's hi-plane loads (A dead after pass 2) under pass 3
        if (it + 1 < NITER) {
            const ushort* nb = wb + (it + 1) * 8192;
#pragma unroll
            for (int ks = 0; ks < 8; ++ks)
                A[ks] = *(const half8*)(nb + ks * 512);
        }
        // pass 3: wl x xh
#pragma unroll
        for (int ks = 0; ks < 8; ++ks) {
            acc0 = __builtin_amdgcn_mfma_f32_32x32x16_f16(Bf[ks], xh0[ks], acc0, 0, 0, 0);
            acc1 = __builtin_amdgcn_mfma_f32_32x32x16_f16(Bf[ks], xh1[ks], acc1, 0, 0, 0);
        }

        // fold 16 option-rows per acc into running scalar argmax
        float lv0 = acc0[0]; int lr0 = 0;
#pragma unroll
        for (int r = 1; r < 16; ++r)
            if (acc0[r] > lv0) { lv0 = acc0[r]; lr0 = r; }   // strict >: earliest row wins
        int li0 = nwb + it * 32 + 4 * half + (lr0 & 3) + 8 * (lr0 >> 2);
        if (lv0 > best0) { best0 = lv0; bidx0 = li0; }

        float lv1 = acc1[0]; int lr1 = 0;
#pragma unroll
        for (int r = 1; r < 16; ++r)
            if (acc1[r] > lv1) { lv1 = acc1[r]; lr1 = r; }
        int li1 = nwb + it * 32 + 4 * half + (lr1 & 3) + 8 * (lr1 >> 2);
        if (lv1 > best1) { best1 = lv1; bidx1 = li1; }
    }

    // merge lane halves (disjoint option rows, same position column)
    {
        float om = __shfl_xor(best0, 32, 64);
        int   oi = __shfl_xor(bidx0, 32, 64);
        if (om > best0 || (om == best0 && oi < bidx0)) { best0 = om; bidx0 = oi; }
        om = __shfl_xor(best1, 32, 64);
        oi = __shfl_xor(bidx1, 32, 64);
        if (om > best1 || (om == best1 && oi < bidx1)) { best1 = om; bidx1 = oi; }
    }
    if (half == 0) {
        red_max[nhalf][msub * 64 + l31]      = best0;
        red_idx[nhalf][msub * 64 + l31]      = bidx0;
        red_max[nhalf][msub * 64 + 32 + l31] = best1;
        red_idx[nhalf][msub * 64 + 32 + l31] = bidx1;
    }
    __syncthreads();

    // gather: out[p0+row, h, :] = cb[h, argmax, :]
    for (int i = tid; i < MTILE * 32; i += 512) {
        int row = i >> 5, ch = i & 31;
        float m0 = red_max[0][row], m1 = red_max[1][row];
        int o = (m1 > m0) ? red_idx[1][row] : red_idx[0][row]; // ties -> smaller o
        float4 v = *(const float4*)(cb + (h * kO + o) * kA + ch * 4);
        *(float4*)(out + ((p0 + row) * kH + h) * kA + ch * 4) = v;
    }
}

extern "C" void kernel_launch(void* const* d_in, const int* in_sizes, int n_in,
                              void* d_out, int out_size, void* d_ws, size_t ws_size,
                              hipStream_t stream) {
    const float* x  = (const float*)d_in[0];   // [4096,16,128] fp32
    const float* w  = (const float*)d_in[1];   // [16,1024,128] fp32
    const float* cb = (const float*)d_in[2];   // [16,1024,128] fp32
    // d_in[3] = temperature: forward value is temperature-independent
    float* out = (float*)d_out;                // [4096,16,128] fp32

    ushort* wpacked = (ushort*)d_ws;           // 8 MiB packed hi+lo planes

    split_w<<<dim3(1024), dim3(256), 0, stream>>>(w, wpacked);
    vq_argmax_gather<<<dim3((kBS / MTILE) * kH), dim3(512), 0, stream>>>(x, wpacked, cb, out);
}